// Round 1
// baseline (241.282 us; speedup 1.0000x reference)
//
#include <hip/hip_runtime.h>

// ---------------------------------------------------------------------------
// GPT-2 style MHA block: qkv = x@W_attn+b; causal softmax(QK^T)V; out@W_proj+b
// B=1, S=4096, D=768, H=12, HD=64.  All heavy math in bf16 MFMA (fp32 accum).
// ---------------------------------------------------------------------------

typedef short bf16x8 __attribute__((ext_vector_type(8)));      // MFMA A/B frag
typedef float f32x4 __attribute__((ext_vector_type(4)));       // MFMA C/D frag
typedef unsigned short u16x8_t __attribute__((ext_vector_type(8)));
typedef unsigned short u16x4_t __attribute__((ext_vector_type(4)));

#define ATT_S  4096
#define ATT_D  768
#define ATT_3D 2304
#define ATT_H  12

__device__ __forceinline__ unsigned short f2b(float f) {
  union { float f; unsigned int u; } v; v.f = f;
  unsigned int r = v.u + 0x7fffu + ((v.u >> 16) & 1u);   // RNE
  return (unsigned short)(r >> 16);
}

__device__ __forceinline__ f32x4 mfma16(bf16x8 a, bf16x8 b, f32x4 c) {
  return __builtin_amdgcn_mfma_f32_16x16x32_bf16(a, b, c, 0, 0, 0);
}

__device__ __forceinline__ void glds16(const void* g, void* l) {
  __builtin_amdgcn_global_load_lds((__attribute__((address_space(1))) void*)g,
                                   (__attribute__((address_space(3))) void*)l,
                                   16, 0, 0);
}

// --------------------------- pre-pass kernels ------------------------------

__global__ __launch_bounds__(256) void convert_f32_bf16(
    const float* __restrict__ in, unsigned short* __restrict__ out, int n4) {
  int i = blockIdx.x * 256 + threadIdx.x;
  if (i >= n4) return;
  float4 v = ((const float4*)in)[i];
  u16x4_t o;
  o[0] = f2b(v.x); o[1] = f2b(v.y); o[2] = f2b(v.z); o[3] = f2b(v.w);
  ((u16x4_t*)out)[i] = o;
}

// W[K][N] f32  ->  WT[N][K] bf16   (both sides coalesced via 32x33 LDS tile)
__global__ __launch_bounds__(256) void transpose_conv(
    const float* __restrict__ W, unsigned short* __restrict__ WT, int K, int N) {
  __shared__ float tile[32][33];
  int bx = blockIdx.x, by = blockIdx.y;
  int tx = threadIdx.x & 31, ty = threadIdx.x >> 5;
#pragma unroll
  for (int k = 0; k < 4; k++)
    tile[ty + k * 8][tx] = W[(size_t)(by * 32 + ty + k * 8) * N + bx * 32 + tx];
  __syncthreads();
#pragma unroll
  for (int k = 0; k < 4; k++)
    WT[(size_t)(bx * 32 + ty + k * 8) * K + by * 32 + tx] = f2b(tile[tx][ty + k * 8]);
}

// --------------------------- bf16 MFMA GEMM --------------------------------
// C[M][N] = A[M][K] @ Bt[N][K]^T + bias.  128x128 tile, BK=32, 4 waves (2x2),
// global_load_lds w=16 with XOR slot swizzle (both sides), XCD-aware bid swz.

template <int BF16_OUT>
__global__ __launch_bounds__(256) void gemm_bias(
    const unsigned short* __restrict__ A, const unsigned short* __restrict__ Bt,
    const float* __restrict__ bias, void* __restrict__ Cout,
    int M, int N, int K) {
  __shared__ unsigned short As[128 * 32];
  __shared__ unsigned short Bs[128 * 32];
  const int t = threadIdx.x;
  const int lane = t & 63;
  const int wave = t >> 6;
  const int wr = wave >> 1, wc = wave & 1;
  const int rl = lane & 15, rg = lane >> 4;

  const int nbn = N >> 7;
  const int nwg = gridDim.x;                  // launched as multiple of 8
  const int bid = blockIdx.x;
  const int cpx = nwg >> 3;
  const int swz = (bid & 7) * cpx + (bid >> 3);
  const int bm = swz / nbn, bn = swz % nbn;

  const unsigned short* Ab = A + (size_t)bm * 128 * K;
  const unsigned short* Bb = Bt + (size_t)bn * 128 * K;

  f32x4 acc[4][4];
#pragma unroll
  for (int m = 0; m < 4; m++)
#pragma unroll
    for (int n = 0; n < 4; n++) acc[m][n] = (f32x4){0.f, 0.f, 0.f, 0.f};

  for (int kt = 0; kt < K; kt += 32) {
    if (kt) __syncthreads();
#pragma unroll
    for (int it = 0; it < 2; ++it) {
      int idx = it * 256 + t;
      int row = idx >> 2;
      int slot = idx & 3;
      int sl2 = slot ^ ((row >> 1) & 3);      // pre-swizzled global source
      unsigned short* ldsA = As + (size_t)(it * 256 + wave * 64) * 8; // wave-uniform
      unsigned short* ldsB = Bs + (size_t)(it * 256 + wave * 64) * 8;
      glds16(Ab + (size_t)row * K + kt + sl2 * 8, ldsA);
      glds16(Bb + (size_t)row * K + kt + sl2 * 8, ldsB);
    }
    __syncthreads();                          // drains vmcnt for gload_lds

    bf16x8 a[4], b[4];
#pragma unroll
    for (int m = 0; m < 4; m++) {
      int row = wr * 64 + m * 16 + rl;
      int sl2 = rg ^ ((row >> 1) & 3);        // swizzled read
      a[m] = *(const bf16x8*)&As[row * 32 + sl2 * 8];
    }
#pragma unroll
    for (int n = 0; n < 4; n++) {
      int row = wc * 64 + n * 16 + rl;
      int sl2 = rg ^ ((row >> 1) & 3);
      b[n] = *(const bf16x8*)&Bs[row * 32 + sl2 * 8];
    }
#pragma unroll
    for (int m = 0; m < 4; m++)
#pragma unroll
      for (int n = 0; n < 4; n++)
        acc[m][n] = mfma16(a[m], b[n], acc[m][n]);
  }

#pragma unroll
  for (int n = 0; n < 4; n++) {
    int col = bn * 128 + wc * 64 + n * 16 + rl;
    float bv = bias[col];
#pragma unroll
    for (int m = 0; m < 4; m++) {
      int row0 = bm * 128 + wr * 64 + m * 16 + rg * 4;
#pragma unroll
      for (int i = 0; i < 4; i++) {
        float v = acc[m][n][i] + bv;
        if (BF16_OUT)
          ((unsigned short*)Cout)[(size_t)(row0 + i) * N + col] = f2b(v);
        else
          ((float*)Cout)[(size_t)(row0 + i) * N + col] = v;
      }
    }
  }
}

// --------------------------- flash attention -------------------------------
// One block = (head, 128 q-rows), 4 waves x 32 q-rows. KV tile = 64 keys.
// Swapped QK^T: S^T = K @ Q^T so key axis is lane-local for softmax.
// No 1/sqrt(HD) scaling (reference applies none).

__global__ __launch_bounds__(256) void attn_fwd(
    const unsigned short* __restrict__ qkv, unsigned short* __restrict__ aout) {
  __shared__ unsigned short Ks[64 * 72];
  __shared__ unsigned short Vt[64 * 72];
  __shared__ unsigned short Ps[4 * 32 * 72];   // per-wave P; Vrow aliases [0..4607]

  const int t = threadIdx.x;
  const int lane = t & 63;
  const int w = t >> 6;
  const int rl = lane & 15, rg = lane >> 4;

  const int bid = blockIdx.x;
  const int h = bid % ATT_H;
  const int qb = 31 - (bid / ATT_H);          // big blocks dispatched first
  const int qbase = qb * 128 + w * 32;
  const int qhi = qbase + 31;

  unsigned short* Vrow = Ps;                  // staging alias (phase-disjoint)
  unsigned short* Pw = Ps + w * (32 * 72);

  // Q fragments, held in registers for the whole kernel
  bf16x8 qf[2][2];
#pragma unroll
  for (int q2 = 0; q2 < 2; q2++)
#pragma unroll
    for (int ks = 0; ks < 2; ks++) {
      int q = qbase + q2 * 16 + rl;
      qf[q2][ks] = *(const bf16x8*)&qkv[(size_t)q * ATT_3D + h * 64 + ks * 32 + rg * 8];
    }

  float mS[2] = {-3.0e38f, -3.0e38f};
  float lS[2] = {0.f, 0.f};
  f32x4 oacc[2][4];
#pragma unroll
  for (int q2 = 0; q2 < 2; q2++)
#pragma unroll
    for (int hf = 0; hf < 4; hf++) oacc[q2][hf] = (f32x4){0.f, 0.f, 0.f, 0.f};

  const int ntiles = (qb * 128 + 128) >> 6;   // 2*qb + 2

  for (int kv = 0; kv < ntiles; ++kv) {
    __syncthreads();                          // prev tile's LDS reads done
    const size_t krow = (size_t)(kv * 64) * ATT_3D;
    // stage K rows + V rows (each wave stages keys w*8..+7 and 32+w*8..+7)
#pragma unroll
    for (int it = 0; it < 2; ++it) {
      int key = it * 32 + w * 8 + (lane >> 3);
      int slot = lane & 7;
      *(u16x8_t*)&Ks[key * 72 + slot * 8] =
          *(const u16x8_t*)&qkv[krow + (size_t)key * ATT_3D + 768 + h * 64 + slot * 8];
      *(u16x8_t*)&Vrow[key * 72 + slot * 8] =
          *(const u16x8_t*)&qkv[krow + (size_t)key * ATT_3D + 1536 + h * 64 + slot * 8];
    }
    // within-wave transpose of this wave's own staged keys -> Vt[hd][key]
#pragma unroll
    for (int kk = 0; kk < 2; ++kk) {
      int kb = w + kk * 4;
      u16x8_t g;
#pragma unroll
      for (int j = 0; j < 8; j++) g[j] = Vrow[(kb * 8 + j) * 72 + lane];
      *(u16x8_t*)&Vt[lane * 72 + kb * 8] = g;
    }
    __syncthreads();
    if (kv * 64 > qhi) continue;              // wave fully above diagonal

    // ---- S^T = K @ Q^T : rows = keys (lane-local regs), cols = q ----
    f32x4 st[4][2];
#pragma unroll
    for (int kf = 0; kf < 4; kf++)
#pragma unroll
      for (int q2 = 0; q2 < 2; q2++) st[kf][q2] = (f32x4){0.f, 0.f, 0.f, 0.f};
#pragma unroll
    for (int ks = 0; ks < 2; ks++) {
      bf16x8 kfr[4];
#pragma unroll
      for (int kf = 0; kf < 4; kf++)
        kfr[kf] = *(const bf16x8*)&Ks[(kf * 16 + rl) * 72 + (ks * 4 + rg) * 8];
#pragma unroll
      for (int kf = 0; kf < 4; kf++)
#pragma unroll
        for (int q2 = 0; q2 < 2; q2++)
          st[kf][q2] = mfma16(kfr[kf], qf[q2][ks], st[kf][q2]);
    }
    // causal mask
    if (kv * 64 + 63 > qbase) {
#pragma unroll
      for (int kf = 0; kf < 4; kf++)
#pragma unroll
        for (int q2 = 0; q2 < 2; q2++)
#pragma unroll
          for (int i = 0; i < 4; i++) {
            int key = kv * 64 + kf * 16 + rg * 4 + i;
            int q = qbase + q2 * 16 + rl;
            if (key > q) st[kf][q2][i] = -3.0e38f;
          }
    }
    // ---- online softmax (per q column; key axis = lane-local + 2 shuffles)
    float fac[2];
#pragma unroll
    for (int q2 = 0; q2 < 2; q2++) {
      float pm = st[0][q2][0];
#pragma unroll
      for (int kf = 0; kf < 4; kf++)
#pragma unroll
        for (int i = 0; i < 4; i++) pm = fmaxf(pm, st[kf][q2][i]);
      pm = fmaxf(pm, __shfl_xor(pm, 16, 64));
      pm = fmaxf(pm, __shfl_xor(pm, 32, 64));
      float mn = fmaxf(mS[q2], pm);
      fac[q2] = __expf(mS[q2] - mn);
      mS[q2] = mn;
      float psum = 0.f;
#pragma unroll
      for (int kf = 0; kf < 4; kf++) {
        u16x4_t pw;
#pragma unroll
        for (int i = 0; i < 4; i++) {
          float p = __expf(st[kf][q2][i] - mn);
          psum += p;
          pw[i] = f2b(p);
        }
        *(u16x4_t*)&Pw[(q2 * 16 + rl) * 72 + kf * 16 + rg * 4] = pw;  // P[q][key]
      }
      psum += __shfl_xor(psum, 16, 64);
      psum += __shfl_xor(psum, 32, 64);
      lS[q2] = lS[q2] * fac[q2] + psum;
    }
    // rescale O accumulator (fetch factor for this lane's acc rows)
#pragma unroll
    for (int q2 = 0; q2 < 2; q2++) {
#pragma unroll
      for (int i = 0; i < 4; i++) {
        float fi = __shfl(fac[q2], rg * 4 + i, 64);
#pragma unroll
        for (int hf = 0; hf < 4; hf++) oacc[q2][hf][i] *= fi;
      }
    }
    // ---- PV : O += P @ V  (P from per-wave LDS, V from transposed Vt) ----
#pragma unroll
    for (int ks2 = 0; ks2 < 2; ks2++) {
      bf16x8 pa[2];
#pragma unroll
      for (int q2 = 0; q2 < 2; q2++)
        pa[q2] = *(const bf16x8*)&Pw[(q2 * 16 + rl) * 72 + ks2 * 32 + rg * 8];
#pragma unroll
      for (int hf = 0; hf < 4; hf++) {
        bf16x8 vb = *(const bf16x8*)&Vt[(hf * 16 + rl) * 72 + (ks2 * 4 + rg) * 8];
#pragma unroll
        for (int q2 = 0; q2 < 2; q2++)
          oacc[q2][hf] = mfma16(pa[q2], vb, oacc[q2][hf]);
      }
    }
  }

  // finalize: divide by row sums, write bf16 [S][768]
#pragma unroll
  for (int q2 = 0; q2 < 2; q2++) {
#pragma unroll
    for (int i = 0; i < 4; i++) {
      float li = __shfl(lS[q2], rg * 4 + i, 64);
      float inv = 1.f / li;
      int q = qbase + q2 * 16 + rg * 4 + i;
#pragma unroll
      for (int hf = 0; hf < 4; hf++) {
        int col = h * 64 + hf * 16 + rl;
        aout[(size_t)q * ATT_D + col] = f2b(oacc[q2][hf][i] * inv);
      }
    }
  }
}

// ------------------------------- launcher ----------------------------------

extern "C" void kernel_launch(void* const* d_in, const int* in_sizes, int n_in,
                              void* d_out, int out_size, void* d_ws, size_t ws_size,
                              hipStream_t stream) {
  const float* x      = (const float*)d_in[0];
  const float* W_attn = (const float*)d_in[1];
  const float* b_attn = (const float*)d_in[2];
  const float* W_proj = (const float*)d_in[3];
  const float* b_proj = (const float*)d_in[4];
  float* out = (float*)d_out;

  char* ws = (char*)d_ws;
  unsigned short* xb  = (unsigned short*)(ws);              //  6,291,456 B
  unsigned short* WaT = (unsigned short*)(ws + 6291456);    //  3,538,944 B
  unsigned short* WpT = (unsigned short*)(ws + 9830400);    //  1,179,648 B
  unsigned short* qkv = (unsigned short*)(ws + 11010048);   // 18,874,368 B
  unsigned short* ao  = (unsigned short*)(ws + 29884416);   //  6,291,456 B

  convert_f32_bf16<<<3072, 256, 0, stream>>>(x, xb, 786432);           // 4096*768/4
  transpose_conv<<<dim3(72, 24), 256, 0, stream>>>(W_attn, WaT, 768, 2304);
  transpose_conv<<<dim3(24, 24), 256, 0, stream>>>(W_proj, WpT, 768, 768);

  gemm_bias<1><<<576, 256, 0, stream>>>(xb, WaT, b_attn, qkv, 4096, 2304, 768);
  attn_fwd<<<384, 256, 0, stream>>>(qkv, ao);
  gemm_bias<0><<<192, 256, 0, stream>>>(ao, WpT, b_proj, out, 4096, 768, 768);
}

// Round 2
// 152.170 us; speedup vs baseline: 1.5856x; 1.5856x over previous
//
#include <hip/hip_runtime.h>

// ---------------------------------------------------------------------------
// GPT-2 style MHA block: qkv = x@W_attn+b; causal softmax(QK^T)V; out@W_proj+b
// B=1, S=4096, D=768, H=12, HD=64.  All heavy math in bf16 MFMA (fp32 accum).
// ---------------------------------------------------------------------------

typedef short bf16x8 __attribute__((ext_vector_type(8)));      // MFMA A/B frag
typedef float f32x4 __attribute__((ext_vector_type(4)));       // MFMA C/D frag
typedef unsigned short u16x8_t __attribute__((ext_vector_type(8)));
typedef unsigned short u16x4_t __attribute__((ext_vector_type(4)));

#define ATT_S  4096
#define ATT_D  768
#define ATT_3D 2304
#define ATT_H  12

__device__ __forceinline__ unsigned short f2b(float f) {
  union { float f; unsigned int u; } v; v.f = f;
  unsigned int r = v.u + 0x7fffu + ((v.u >> 16) & 1u);   // RNE
  return (unsigned short)(r >> 16);
}

__device__ __forceinline__ f32x4 mfma16(bf16x8 a, bf16x8 b, f32x4 c) {
  return __builtin_amdgcn_mfma_f32_16x16x32_bf16(a, b, c, 0, 0, 0);
}

__device__ __forceinline__ void glds16(const void* g, void* l) {
  __builtin_amdgcn_global_load_lds((__attribute__((address_space(1))) void*)g,
                                   (__attribute__((address_space(3))) void*)l,
                                   16, 0, 0);
}

// --------------------------- pre-pass kernels ------------------------------

__global__ __launch_bounds__(256) void convert_f32_bf16(
    const float* __restrict__ in, unsigned short* __restrict__ out, int n4) {
  int i = blockIdx.x * 256 + threadIdx.x;
  if (i >= n4) return;
  float4 v = ((const float4*)in)[i];
  u16x4_t o;
  o[0] = f2b(v.x); o[1] = f2b(v.y); o[2] = f2b(v.z); o[3] = f2b(v.w);
  ((u16x4_t*)out)[i] = o;
}

// W[K][N] f32  ->  WT[N][K] bf16   (both sides coalesced via 32x33 LDS tile)
__global__ __launch_bounds__(256) void transpose_conv(
    const float* __restrict__ W, unsigned short* __restrict__ WT, int K, int N) {
  __shared__ float tile[32][33];
  int bx = blockIdx.x, by = blockIdx.y;
  int tx = threadIdx.x & 31, ty = threadIdx.x >> 5;
#pragma unroll
  for (int k = 0; k < 4; k++)
    tile[ty + k * 8][tx] = W[(size_t)(by * 32 + ty + k * 8) * N + bx * 32 + tx];
  __syncthreads();
#pragma unroll
  for (int k = 0; k < 4; k++)
    WT[(size_t)(bx * 32 + ty + k * 8) * K + by * 32 + tx] = f2b(tile[tx][ty + k * 8]);
}

// --------------------------- bf16 MFMA GEMM --------------------------------
// C[M][N] = A[M][K] @ Bt[N][K]^T + bias.  128x128 tile, BK=32, 4 waves (2x2),
// global_load_lds w=16 with XOR slot swizzle (both sides), XCD-aware bid swz.

template <int BF16_OUT>
__global__ __launch_bounds__(256) void gemm_bias(
    const unsigned short* __restrict__ A, const unsigned short* __restrict__ Bt,
    const float* __restrict__ bias, void* __restrict__ Cout,
    int M, int N, int K) {
  __shared__ unsigned short As[128 * 32];
  __shared__ unsigned short Bs[128 * 32];
  const int t = threadIdx.x;
  const int lane = t & 63;
  const int wave = t >> 6;
  const int wr = wave >> 1, wc = wave & 1;
  const int rl = lane & 15, rg = lane >> 4;

  const int nbn = N >> 7;
  const int nwg = gridDim.x;                  // launched as multiple of 8
  const int bid = blockIdx.x;
  const int cpx = nwg >> 3;
  const int swz = (bid & 7) * cpx + (bid >> 3);
  const int bm = swz / nbn, bn = swz % nbn;

  const unsigned short* Ab = A + (size_t)bm * 128 * K;
  const unsigned short* Bb = Bt + (size_t)bn * 128 * K;

  f32x4 acc[4][4];
#pragma unroll
  for (int m = 0; m < 4; m++)
#pragma unroll
    for (int n = 0; n < 4; n++) acc[m][n] = (f32x4){0.f, 0.f, 0.f, 0.f};

  for (int kt = 0; kt < K; kt += 32) {
    if (kt) __syncthreads();
#pragma unroll
    for (int it = 0; it < 2; ++it) {
      int idx = it * 256 + t;
      int row = idx >> 2;
      int slot = idx & 3;
      int sl2 = slot ^ ((row >> 1) & 3);      // pre-swizzled global source
      unsigned short* ldsA = As + (size_t)(it * 256 + wave * 64) * 8; // wave-uniform
      unsigned short* ldsB = Bs + (size_t)(it * 256 + wave * 64) * 8;
      glds16(Ab + (size_t)row * K + kt + sl2 * 8, ldsA);
      glds16(Bb + (size_t)row * K + kt + sl2 * 8, ldsB);
    }
    __syncthreads();                          // drains vmcnt for gload_lds

    bf16x8 a[4], b[4];
#pragma unroll
    for (int m = 0; m < 4; m++) {
      int row = wr * 64 + m * 16 + rl;
      int sl2 = rg ^ ((row >> 1) & 3);        // swizzled read
      a[m] = *(const bf16x8*)&As[row * 32 + sl2 * 8];
    }
#pragma unroll
    for (int n = 0; n < 4; n++) {
      int row = wc * 64 + n * 16 + rl;
      int sl2 = rg ^ ((row >> 1) & 3);
      b[n] = *(const bf16x8*)&Bs[row * 32 + sl2 * 8];
    }
#pragma unroll
    for (int m = 0; m < 4; m++)
#pragma unroll
      for (int n = 0; n < 4; n++)
        acc[m][n] = mfma16(a[m], b[n], acc[m][n]);
  }

#pragma unroll
  for (int n = 0; n < 4; n++) {
    int col = bn * 128 + wc * 64 + n * 16 + rl;
    float bv = bias[col];
#pragma unroll
    for (int m = 0; m < 4; m++) {
      int row0 = bm * 128 + wr * 64 + m * 16 + rg * 4;
#pragma unroll
      for (int i = 0; i < 4; i++) {
        float v = acc[m][n][i] + bv;
        if (BF16_OUT)
          ((unsigned short*)Cout)[(size_t)(row0 + i) * N + col] = f2b(v);
        else
          ((float*)Cout)[(size_t)(row0 + i) * N + col] = v;
      }
    }
  }
}

// --------------------------- flash attention -------------------------------
// One block = (head, 64 q-rows), 4 waves x 16 q-rows. KV tile = 64 keys.
// Swapped QK^T (S^T = K @ Q^T) -> key axis lane-local for softmax reduce.
// Double-buffered K/V LDS, one barrier per tile, async reg-staged prefetch
// (T14), defer-max rescale skip (T13), setprio around MFMA (T5).
// No 1/sqrt(HD) scaling (reference applies none).

__global__ __launch_bounds__(256) void attn_fwd(
    const unsigned short* __restrict__ qkv, unsigned short* __restrict__ aout) {
  __shared__ unsigned short Kb[2][64 * 72];   // K rows   [key][hd]
  __shared__ unsigned short Vb[2][64 * 72];   // V^T rows [hd][key]
  __shared__ unsigned short Ps[4][16 * 72];   // per-wave P / V-row scratch

  const int tid = threadIdx.x;
  const int lane = tid & 63;
  const int w = tid >> 6;
  const int rl = lane & 15, rg = lane >> 4;

  const int bid = blockIdx.x;
  const int h = bid % ATT_H;
  const int qb = 63 - (bid / ATT_H);          // long blocks dispatched first
  const int qbase = qb * 64 + w * 16;
  const int nt = qb + 1;

  unsigned short* Pw = Ps[w];
  const int skey = lane >> 3;                 // staging: key within group of 8
  const int slot = lane & 7;                  // staging: 8-elem hd slot

  // Q fragments, in registers for the whole kernel
  bf16x8 qf[2];
#pragma unroll
  for (int ks = 0; ks < 2; ks++)
    qf[ks] = *(const bf16x8*)&qkv[(size_t)(qbase + rl) * ATT_3D + h * 64 + ks * 32 + rg * 8];

  float mS = -3.0e38f, lS = 0.f;
  f32x4 oacc[4];
#pragma unroll
  for (int hf = 0; hf < 4; hf++) oacc[hf] = (f32x4){0.f, 0.f, 0.f, 0.f};

  u16x8_t kr[2], vr[2];
  const size_t gstep = (size_t)64 * ATT_3D;
  size_t gbase = (size_t)(w * 8 + skey) * ATT_3D + 768 + h * 64 + slot * 8;

  // prologue: stage tile 0
#pragma unroll
  for (int it = 0; it < 2; ++it) {
    kr[it] = *(const u16x8_t*)&qkv[gbase + it * 32 * ATT_3D];
    vr[it] = *(const u16x8_t*)&qkv[gbase + it * 32 * ATT_3D + 768];
  }
  {
#pragma unroll
    for (int it = 0; it < 2; ++it) {
      int key = it * 32 + w * 8 + skey;
      *(u16x8_t*)&Kb[0][key * 72 + slot * 8] = kr[it];
      *(u16x8_t*)&Pw[(it * 8 + skey) * 72 + slot * 8] = vr[it];
    }
#pragma unroll
    for (int kk = 0; kk < 2; ++kk) {
      u16x8_t g;
#pragma unroll
      for (int j = 0; j < 8; j++) g[j] = Pw[(kk * 8 + j) * 72 + lane];
      *(u16x8_t*)&Vb[0][lane * 72 + kk * 32 + w * 8] = g;
    }
  }
  __syncthreads();

  for (int t = 0; t < nt; ++t) {
    const int cur = t & 1;
    const bool pref = (t + 1 < nt);
    if (pref) {                               // issue next-tile loads early
      size_t gb = gbase + (size_t)(t + 1) * gstep;
#pragma unroll
      for (int it = 0; it < 2; ++it) {
        kr[it] = *(const u16x8_t*)&qkv[gb + it * 32 * ATT_3D];
        vr[it] = *(const u16x8_t*)&qkv[gb + it * 32 * ATT_3D + 768];
      }
    }

    // ---- S^T = K @ Q^T ----
    f32x4 st[4];
#pragma unroll
    for (int kf = 0; kf < 4; kf++) st[kf] = (f32x4){0.f, 0.f, 0.f, 0.f};
    __builtin_amdgcn_s_setprio(1);
#pragma unroll
    for (int ks = 0; ks < 2; ks++) {
#pragma unroll
      for (int kf = 0; kf < 4; kf++) {
        bf16x8 kfr = *(const bf16x8*)&Kb[cur][(kf * 16 + rl) * 72 + (ks * 4 + rg) * 8];
        st[kf] = mfma16(kfr, qf[ks], st[kf]);
      }
    }
    __builtin_amdgcn_s_setprio(0);

    if (t == nt - 1) {                        // causal mask (only last tile)
#pragma unroll
      for (int kf = 0; kf < 4; kf++)
#pragma unroll
        for (int i = 0; i < 4; i++) {
          int key = t * 64 + kf * 16 + rg * 4 + i;
          if (key > qbase + rl) st[kf][i] = -3.0e38f;
        }
    }

    // ---- online softmax (key axis lane-local + 2 shuffles) ----
    float pm = st[0][0];
#pragma unroll
    for (int kf = 0; kf < 4; kf++)
#pragma unroll
      for (int i = 0; i < 4; i++) pm = fmaxf(pm, st[kf][i]);
    pm = fmaxf(pm, __shfl_xor(pm, 16, 64));
    pm = fmaxf(pm, __shfl_xor(pm, 32, 64));
    if (!__all(pm - mS <= 8.f)) {             // defer-max: rescale rarely
      float mn = fmaxf(mS, pm);
      float fac = __expf(mS - mn);
      mS = mn;
      lS *= fac;
#pragma unroll
      for (int i = 0; i < 4; i++) {
        float fi = __shfl(fac, rg * 4 + i, 64);
#pragma unroll
        for (int hf = 0; hf < 4; hf++) oacc[hf][i] *= fi;
      }
    }
    float psum = 0.f;
#pragma unroll
    for (int kf = 0; kf < 4; kf++) {
      u16x4_t pw4;
#pragma unroll
      for (int i = 0; i < 4; i++) {
        float p = __expf(st[kf][i] - mS);
        psum += p;
        pw4[i] = f2b(p);
      }
      *(u16x4_t*)&Pw[rl * 72 + kf * 16 + rg * 4] = pw4;   // P[q][key]
    }
    psum += __shfl_xor(psum, 16, 64);
    psum += __shfl_xor(psum, 32, 64);
    lS += psum;

    // ---- PV : O += P @ V ----
    __builtin_amdgcn_s_setprio(1);
#pragma unroll
    for (int ks2 = 0; ks2 < 2; ks2++) {
      bf16x8 pa = *(const bf16x8*)&Pw[rl * 72 + ks2 * 32 + rg * 8];
#pragma unroll
      for (int hf = 0; hf < 4; hf++) {
        bf16x8 vbf = *(const bf16x8*)&Vb[cur][(hf * 16 + rl) * 72 + (ks2 * 4 + rg) * 8];
        oacc[hf] = mfma16(pa, vbf, oacc[hf]);
      }
    }
    __builtin_amdgcn_s_setprio(0);

    if (pref) {                               // write-late: LDS for t+1
      const int nxt = cur ^ 1;
#pragma unroll
      for (int it = 0; it < 2; ++it) {
        int key = it * 32 + w * 8 + skey;
        *(u16x8_t*)&Kb[nxt][key * 72 + slot * 8] = kr[it];
        *(u16x8_t*)&Pw[(it * 8 + skey) * 72 + slot * 8] = vr[it];
      }
#pragma unroll
      for (int kk = 0; kk < 2; ++kk) {        // within-wave V transpose
        u16x8_t g;
#pragma unroll
        for (int j = 0; j < 8; j++) g[j] = Pw[(kk * 8 + j) * 72 + lane];
        *(u16x8_t*)&Vb[nxt][lane * 72 + kk * 32 + w * 8] = g;
      }
    }
    __syncthreads();                          // one barrier per tile
  }

  // finalize: divide by row sums, write bf16 [S][768]
#pragma unroll
  for (int i = 0; i < 4; i++) {
    float li = __shfl(lS, rg * 4 + i, 64);
    float inv = 1.f / li;
    int q = qbase + rg * 4 + i;
#pragma unroll
    for (int hf = 0; hf < 4; hf++)
      aout[(size_t)q * ATT_D + h * 64 + hf * 16 + rl] = f2b(oacc[hf][i] * inv);
  }
}

// ------------------------------- launcher ----------------------------------

extern "C" void kernel_launch(void* const* d_in, const int* in_sizes, int n_in,
                              void* d_out, int out_size, void* d_ws, size_t ws_size,
                              hipStream_t stream) {
  const float* x      = (const float*)d_in[0];
  const float* W_attn = (const float*)d_in[1];
  const float* b_attn = (const float*)d_in[2];
  const float* W_proj = (const float*)d_in[3];
  const float* b_proj = (const float*)d_in[4];
  float* out = (float*)d_out;

  char* ws = (char*)d_ws;
  unsigned short* xb  = (unsigned short*)(ws);              //  6,291,456 B
  unsigned short* WaT = (unsigned short*)(ws + 6291456);    //  3,538,944 B
  unsigned short* WpT = (unsigned short*)(ws + 9830400);    //  1,179,648 B
  unsigned short* qkv = (unsigned short*)(ws + 11010048);   // 18,874,368 B
  unsigned short* ao  = (unsigned short*)(ws + 29884416);   //  6,291,456 B

  convert_f32_bf16<<<3072, 256, 0, stream>>>(x, xb, 786432);           // 4096*768/4
  transpose_conv<<<dim3(72, 24), 256, 0, stream>>>(W_attn, WaT, 768, 2304);
  transpose_conv<<<dim3(24, 24), 256, 0, stream>>>(W_proj, WpT, 768, 768);

  gemm_bias<1><<<576, 256, 0, stream>>>(xb, WaT, b_attn, qkv, 4096, 2304, 768);
  attn_fwd<<<768, 256, 0, stream>>>(qkv, ao);
  gemm_bias<0><<<192, 256, 0, stream>>>(ao, WpT, b_proj, out, 4096, 768, 768);
}

// Round 3
// 148.416 us; speedup vs baseline: 1.6257x; 1.0253x over previous
//
#include <hip/hip_runtime.h>

// ---------------------------------------------------------------------------
// GPT-2 style MHA block: qkv = x@W_attn+b; causal softmax(QK^T)V; out@W_proj+b
// B=1, S=4096, D=768, H=12, HD=64.  All heavy math in bf16 MFMA (fp32 accum).
// ---------------------------------------------------------------------------

typedef short bf16x8 __attribute__((ext_vector_type(8)));      // MFMA A/B frag
typedef float f32x4 __attribute__((ext_vector_type(4)));       // MFMA C/D frag
typedef unsigned short u16x8_t __attribute__((ext_vector_type(8)));
typedef unsigned short u16x4_t __attribute__((ext_vector_type(4)));

#define ATT_S  4096
#define ATT_D  768
#define ATT_3D 2304
#define ATT_H  12
#define LOG2E  1.44269504089f

__device__ __forceinline__ unsigned short f2b(float f) {
  union { float f; unsigned int u; } v; v.f = f;
  unsigned int r = v.u + 0x7fffu + ((v.u >> 16) & 1u);   // RNE
  return (unsigned short)(r >> 16);
}

__device__ __forceinline__ f32x4 mfma16(bf16x8 a, bf16x8 b, f32x4 c) {
  return __builtin_amdgcn_mfma_f32_16x16x32_bf16(a, b, c, 0, 0, 0);
}

__device__ __forceinline__ void glds16(const void* g, void* l) {
  __builtin_amdgcn_global_load_lds((__attribute__((address_space(1))) void*)g,
                                   (__attribute__((address_space(3))) void*)l,
                                   16, 0, 0);
}

// element offset of the 16B chunk c in row `row` of a pitch-64 bf16 LDS tile,
// with XOR slot swizzle (T2): spreads row-varying b128 reads across banks.
__device__ __forceinline__ int swz8(int row, int c) {
  return row * 64 + ((c ^ (row & 7)) << 3);
}

// --------------------------- pre-pass kernels ------------------------------

__global__ __launch_bounds__(256) void convert_f32_bf16(
    const float* __restrict__ in, unsigned short* __restrict__ out, int n4) {
  int i = blockIdx.x * 256 + threadIdx.x;
  if (i >= n4) return;
  float4 v = ((const float4*)in)[i];
  u16x4_t o;
  o[0] = f2b(v.x); o[1] = f2b(v.y); o[2] = f2b(v.z); o[3] = f2b(v.w);
  ((u16x4_t*)out)[i] = o;
}

// W[K][N] f32  ->  WT[N][K] bf16   (both sides coalesced via 32x33 LDS tile)
__global__ __launch_bounds__(256) void transpose_conv(
    const float* __restrict__ W, unsigned short* __restrict__ WT, int K, int N) {
  __shared__ float tile[32][33];
  int bx = blockIdx.x, by = blockIdx.y;
  int tx = threadIdx.x & 31, ty = threadIdx.x >> 5;
#pragma unroll
  for (int k = 0; k < 4; k++)
    tile[ty + k * 8][tx] = W[(size_t)(by * 32 + ty + k * 8) * N + bx * 32 + tx];
  __syncthreads();
#pragma unroll
  for (int k = 0; k < 4; k++)
    WT[(size_t)(bx * 32 + ty + k * 8) * K + by * 32 + tx] = f2b(tile[tx][ty + k * 8]);
}

// --------------------------- bf16 MFMA GEMM --------------------------------
// C[M][N] = A[M][K] @ Bt[N][K]^T + bias.  128x128 tile, BK=32, 4 waves (2x2),
// global_load_lds w=16 with XOR slot swizzle (both sides), XCD-aware bid swz.

template <int BF16_OUT>
__global__ __launch_bounds__(256) void gemm_bias(
    const unsigned short* __restrict__ A, const unsigned short* __restrict__ Bt,
    const float* __restrict__ bias, void* __restrict__ Cout,
    int M, int N, int K) {
  __shared__ unsigned short As[128 * 32];
  __shared__ unsigned short Bs[128 * 32];
  const int t = threadIdx.x;
  const int lane = t & 63;
  const int wave = t >> 6;
  const int wr = wave >> 1, wc = wave & 1;
  const int rl = lane & 15, rg = lane >> 4;

  const int nbn = N >> 7;
  const int nwg = gridDim.x;                  // launched as multiple of 8
  const int bid = blockIdx.x;
  const int cpx = nwg >> 3;
  const int swz = (bid & 7) * cpx + (bid >> 3);
  const int bm = swz / nbn, bn = swz % nbn;

  const unsigned short* Ab = A + (size_t)bm * 128 * K;
  const unsigned short* Bb = Bt + (size_t)bn * 128 * K;

  f32x4 acc[4][4];
#pragma unroll
  for (int m = 0; m < 4; m++)
#pragma unroll
    for (int n = 0; n < 4; n++) acc[m][n] = (f32x4){0.f, 0.f, 0.f, 0.f};

  for (int kt = 0; kt < K; kt += 32) {
    if (kt) __syncthreads();
#pragma unroll
    for (int it = 0; it < 2; ++it) {
      int idx = it * 256 + t;
      int row = idx >> 2;
      int slot = idx & 3;
      int sl2 = slot ^ ((row >> 1) & 3);      // pre-swizzled global source
      unsigned short* ldsA = As + (size_t)(it * 256 + wave * 64) * 8; // wave-uniform
      unsigned short* ldsB = Bs + (size_t)(it * 256 + wave * 64) * 8;
      glds16(Ab + (size_t)row * K + kt + sl2 * 8, ldsA);
      glds16(Bb + (size_t)row * K + kt + sl2 * 8, ldsB);
    }
    __syncthreads();                          // drains vmcnt for gload_lds

    bf16x8 a[4], b[4];
#pragma unroll
    for (int m = 0; m < 4; m++) {
      int row = wr * 64 + m * 16 + rl;
      int sl2 = rg ^ ((row >> 1) & 3);        // swizzled read
      a[m] = *(const bf16x8*)&As[row * 32 + sl2 * 8];
    }
#pragma unroll
    for (int n = 0; n < 4; n++) {
      int row = wc * 64 + n * 16 + rl;
      int sl2 = rg ^ ((row >> 1) & 3);
      b[n] = *(const bf16x8*)&Bs[row * 32 + sl2 * 8];
    }
#pragma unroll
    for (int m = 0; m < 4; m++)
#pragma unroll
      for (int n = 0; n < 4; n++)
        acc[m][n] = mfma16(a[m], b[n], acc[m][n]);
  }

#pragma unroll
  for (int n = 0; n < 4; n++) {
    int col = bn * 128 + wc * 64 + n * 16 + rl;
    float bv = bias[col];
#pragma unroll
    for (int m = 0; m < 4; m++) {
      int row0 = bm * 128 + wr * 64 + m * 16 + rg * 4;
#pragma unroll
      for (int i = 0; i < 4; i++) {
        float v = acc[m][n][i] + bv;
        if (BF16_OUT)
          ((unsigned short*)Cout)[(size_t)(row0 + i) * N + col] = f2b(v);
        else
          ((float*)Cout)[(size_t)(row0 + i) * N + col] = v;
      }
    }
  }
}

// --------------------------- flash attention -------------------------------
// One block = (head, 64 q-rows), 4 waves x 16 q-rows. KV tile = 64 keys.
// Swapped QK^T (S^T = K @ Q^T) -> key axis lane-local for softmax reduce.
// Double-buffered K/V LDS (pitch 64, XOR slot swizzle = conflict-free b128),
// one barrier per tile, async reg-staged prefetch (T14), defer-max (T13),
// setprio around MFMA (T5).  LDS = 40960 B -> 4 blocks/CU.
// No 1/sqrt(HD) scaling (reference applies none).

__global__ __launch_bounds__(256) void attn_fwd(
    const unsigned short* __restrict__ qkv, unsigned short* __restrict__ aout) {
  __shared__ unsigned short Kb[2][64 * 64];   // K rows   [key][hd]   (swz)
  __shared__ unsigned short Vb[2][64 * 64];   // V^T rows [hd][key]   (swz)
  __shared__ unsigned short Ps[4][16 * 64];   // per-wave P / V-row scratch (swz)

  const int tid = threadIdx.x;
  const int lane = tid & 63;
  const int w = tid >> 6;
  const int rl = lane & 15, rg = lane >> 4;

  const int bid = blockIdx.x;
  const int h = bid % ATT_H;
  const int qb = 63 - (bid / ATT_H);          // long blocks dispatched first
  const int qbase = qb * 64 + w * 16;
  const int nt = qb + 1;

  unsigned short* Pw = Ps[w];
  const int skey = lane >> 3;                 // staging: key within group of 8
  const int slot = lane & 7;                  // staging: 8-elem hd slot

  // Q fragments, in registers for the whole kernel
  bf16x8 qf[2];
#pragma unroll
  for (int ks = 0; ks < 2; ks++)
    qf[ks] = *(const bf16x8*)&qkv[(size_t)(qbase + rl) * ATT_3D + h * 64 + ks * 32 + rg * 8];

  float mS = -3.0e38f, lS = 0.f;
  f32x4 oacc[4];
#pragma unroll
  for (int hf = 0; hf < 4; hf++) oacc[hf] = (f32x4){0.f, 0.f, 0.f, 0.f};

  u16x8_t kr[2], vr[2];
  const size_t gstep = (size_t)64 * ATT_3D;
  size_t gbase = (size_t)(w * 8 + skey) * ATT_3D + 768 + h * 64 + slot * 8;

  // prologue: stage tile 0
#pragma unroll
  for (int it = 0; it < 2; ++it) {
    kr[it] = *(const u16x8_t*)&qkv[gbase + it * 32 * ATT_3D];
    vr[it] = *(const u16x8_t*)&qkv[gbase + it * 32 * ATT_3D + 768];
  }
  {
#pragma unroll
    for (int it = 0; it < 2; ++it) {
      int key = it * 32 + w * 8 + skey;
      *(u16x8_t*)&Kb[0][swz8(key, slot)] = kr[it];
      *(u16x8_t*)&Pw[swz8(it * 8 + skey, slot)] = vr[it];
    }
#pragma unroll
    for (int kk = 0; kk < 2; ++kk) {
      u16x8_t g;
#pragma unroll
      for (int j = 0; j < 8; j++)
        g[j] = Pw[swz8(kk * 8 + j, lane >> 3) + (lane & 7)];
      *(u16x8_t*)&Vb[0][swz8(lane, kk * 4 + w)] = g;
    }
  }
  __syncthreads();

  for (int t = 0; t < nt; ++t) {
    const int cur = t & 1;
    const bool pref = (t + 1 < nt);
    if (pref) {                               // issue next-tile loads early
      size_t gb = gbase + (size_t)(t + 1) * gstep;
#pragma unroll
      for (int it = 0; it < 2; ++it) {
        kr[it] = *(const u16x8_t*)&qkv[gb + it * 32 * ATT_3D];
        vr[it] = *(const u16x8_t*)&qkv[gb + it * 32 * ATT_3D + 768];
      }
    }

    // ---- S^T = K @ Q^T ----
    f32x4 st[4];
#pragma unroll
    for (int kf = 0; kf < 4; kf++) st[kf] = (f32x4){0.f, 0.f, 0.f, 0.f};
    __builtin_amdgcn_s_setprio(1);
#pragma unroll
    for (int ks = 0; ks < 2; ks++) {
#pragma unroll
      for (int kf = 0; kf < 4; kf++) {
        bf16x8 kfr = *(const bf16x8*)&Kb[cur][swz8(kf * 16 + rl, ks * 4 + rg)];
        st[kf] = mfma16(kfr, qf[ks], st[kf]);
      }
    }
    __builtin_amdgcn_s_setprio(0);

    if (t == nt - 1) {                        // causal mask (only last tile)
#pragma unroll
      for (int kf = 0; kf < 4; kf++)
#pragma unroll
        for (int i = 0; i < 4; i++) {
          int key = t * 64 + kf * 16 + rg * 4 + i;
          if (key > qbase + rl) st[kf][i] = -3.0e38f;
        }
    }

    // ---- online softmax (key axis lane-local + 2 shuffles) ----
    float pm = st[0][0];
#pragma unroll
    for (int kf = 0; kf < 4; kf++)
#pragma unroll
      for (int i = 0; i < 4; i++) pm = fmaxf(pm, st[kf][i]);
    pm = fmaxf(pm, __shfl_xor(pm, 16, 64));
    pm = fmaxf(pm, __shfl_xor(pm, 32, 64));
    if (!__all(pm - mS <= 8.f)) {             // defer-max: rescale rarely
      float mn = fmaxf(mS, pm);
      float fac = __expf(mS - mn);
      mS = mn;
      lS *= fac;
#pragma unroll
      for (int i = 0; i < 4; i++) {
        float fi = __shfl(fac, rg * 4 + i, 64);
#pragma unroll
        for (int hf = 0; hf < 4; hf++) oacc[hf][i] *= fi;
      }
    }
    const float mC = mS * LOG2E;              // exp(s-m) = exp2(s*log2e - mC)
    float psum = 0.f;
#pragma unroll
    for (int kf = 0; kf < 4; kf++) {
      u16x4_t pw4;
#pragma unroll
      for (int i = 0; i < 4; i++) {
        float p = __builtin_amdgcn_exp2f(fmaf(st[kf][i], LOG2E, -mC));
        psum += p;
        pw4[i] = f2b(p);
      }
      *(u16x4_t*)&Pw[swz8(rl, kf * 2 + (rg >> 1)) + (rg & 1) * 4] = pw4;
    }
    psum += __shfl_xor(psum, 16, 64);
    psum += __shfl_xor(psum, 32, 64);
    lS += psum;

    // ---- PV : O += P @ V ----
    __builtin_amdgcn_s_setprio(1);
#pragma unroll
    for (int ks2 = 0; ks2 < 2; ks2++) {
      bf16x8 pa = *(const bf16x8*)&Pw[swz8(rl, ks2 * 4 + rg)];
#pragma unroll
      for (int hf = 0; hf < 4; hf++) {
        bf16x8 vbf = *(const bf16x8*)&Vb[cur][swz8(hf * 16 + rl, ks2 * 4 + rg)];
        oacc[hf] = mfma16(pa, vbf, oacc[hf]);
      }
    }
    __builtin_amdgcn_s_setprio(0);

    if (pref) {                               // write-late: LDS for t+1
      const int nxt = cur ^ 1;
#pragma unroll
      for (int it = 0; it < 2; ++it) {
        int key = it * 32 + w * 8 + skey;
        *(u16x8_t*)&Kb[nxt][swz8(key, slot)] = kr[it];
        *(u16x8_t*)&Pw[swz8(it * 8 + skey, slot)] = vr[it];
      }
#pragma unroll
      for (int kk = 0; kk < 2; ++kk) {        // within-wave V transpose
        u16x8_t g;
#pragma unroll
        for (int j = 0; j < 8; j++)
          g[j] = Pw[swz8(kk * 8 + j, lane >> 3) + (lane & 7)];
        *(u16x8_t*)&Vb[nxt][swz8(lane, kk * 4 + w)] = g;
      }
    }
    __syncthreads();                          // one barrier per tile
  }

  // finalize: divide by row sums, write bf16 [S][768]
#pragma unroll
  for (int i = 0; i < 4; i++) {
    float li = __shfl(lS, rg * 4 + i, 64);
    float inv = 1.f / li;
    int q = qbase + rg * 4 + i;
#pragma unroll
    for (int hf = 0; hf < 4; hf++)
      aout[(size_t)q * ATT_D + h * 64 + hf * 16 + rl] = f2b(oacc[hf][i] * inv);
  }
}

// ------------------------------- launcher ----------------------------------

extern "C" void kernel_launch(void* const* d_in, const int* in_sizes, int n_in,
                              void* d_out, int out_size, void* d_ws, size_t ws_size,
                              hipStream_t stream) {
  const float* x      = (const float*)d_in[0];
  const float* W_attn = (const float*)d_in[1];
  const float* b_attn = (const float*)d_in[2];
  const float* W_proj = (const float*)d_in[3];
  const float* b_proj = (const float*)d_in[4];
  float* out = (float*)d_out;

  char* ws = (char*)d_ws;
  unsigned short* xb  = (unsigned short*)(ws);              //  6,291,456 B
  unsigned short* WaT = (unsigned short*)(ws + 6291456);    //  3,538,944 B
  unsigned short* WpT = (unsigned short*)(ws + 9830400);    //  1,179,648 B
  unsigned short* qkv = (unsigned short*)(ws + 11010048);   // 18,874,368 B
  unsigned short* ao  = (unsigned short*)(ws + 29884416);   //  6,291,456 B

  convert_f32_bf16<<<3072, 256, 0, stream>>>(x, xb, 786432);           // 4096*768/4
  transpose_conv<<<dim3(72, 24), 256, 0, stream>>>(W_attn, WaT, 768, 2304);
  transpose_conv<<<dim3(24, 24), 256, 0, stream>>>(W_proj, WpT, 768, 768);

  gemm_bias<1><<<576, 256, 0, stream>>>(xb, WaT, b_attn, qkv, 4096, 2304, 768);
  attn_fwd<<<768, 256, 0, stream>>>(qkv, ao);
  gemm_bias<0><<<192, 256, 0, stream>>>(ao, WpT, b_proj, out, 4096, 768, 768);
}

// Round 4
// 129.120 us; speedup vs baseline: 1.8687x; 1.1494x over previous
//
#include <hip/hip_runtime.h>

// ---------------------------------------------------------------------------
// GPT-2 style MHA block: qkv = x@W_attn+b; causal softmax(QK^T)V; out@W_proj+b
// B=1, S=4096, D=768, H=12, HD=64.  All heavy math in bf16 MFMA (fp32 accum).
// Attention uses split-K (flash-decoding): blocks = (head, q-strip64, key
// chunk of <=1024), partials merged by attn_combine.
// ---------------------------------------------------------------------------

typedef short bf16x8 __attribute__((ext_vector_type(8)));      // MFMA A/B frag
typedef float f32x4 __attribute__((ext_vector_type(4)));       // MFMA C/D frag
typedef unsigned short u16x8_t __attribute__((ext_vector_type(8)));
typedef unsigned short u16x4_t __attribute__((ext_vector_type(4)));

#define ATT_S  4096
#define ATT_D  768
#define ATT_3D 2304
#define ATT_H  12
#define LOG2E  1.44269504089f

__device__ __forceinline__ unsigned short f2b(float f) {
  union { float f; unsigned int u; } v; v.f = f;
  unsigned int r = v.u + 0x7fffu + ((v.u >> 16) & 1u);   // RNE
  return (unsigned short)(r >> 16);
}
__device__ __forceinline__ float b2f(unsigned short b) {
  union { unsigned int u; float f; } v; v.u = ((unsigned int)b) << 16;
  return v.f;
}

__device__ __forceinline__ f32x4 mfma16(bf16x8 a, bf16x8 b, f32x4 c) {
  return __builtin_amdgcn_mfma_f32_16x16x32_bf16(a, b, c, 0, 0, 0);
}

__device__ __forceinline__ void glds16(const void* g, void* l) {
  __builtin_amdgcn_global_load_lds((__attribute__((address_space(1))) void*)g,
                                   (__attribute__((address_space(3))) void*)l,
                                   16, 0, 0);
}

// element offset of the 16B chunk c in row `row` of a pitch-64 bf16 LDS tile,
// with XOR slot swizzle (T2): spreads row-varying b128 reads across banks.
__device__ __forceinline__ int swz8(int row, int c) {
  return row * 64 + ((c ^ (row & 7)) << 3);
}

// --------------------------- pre-pass kernels ------------------------------

__global__ __launch_bounds__(256) void convert_f32_bf16(
    const float* __restrict__ in, unsigned short* __restrict__ out, int n4) {
  int i = blockIdx.x * 256 + threadIdx.x;
  if (i >= n4) return;
  float4 v = ((const float4*)in)[i];
  u16x4_t o;
  o[0] = f2b(v.x); o[1] = f2b(v.y); o[2] = f2b(v.z); o[3] = f2b(v.w);
  ((u16x4_t*)out)[i] = o;
}

// W[K][N] f32  ->  WT[N][K] bf16   (both sides coalesced via 32x33 LDS tile)
__global__ __launch_bounds__(256) void transpose_conv(
    const float* __restrict__ W, unsigned short* __restrict__ WT, int K, int N) {
  __shared__ float tile[32][33];
  int bx = blockIdx.x, by = blockIdx.y;
  int tx = threadIdx.x & 31, ty = threadIdx.x >> 5;
#pragma unroll
  for (int k = 0; k < 4; k++)
    tile[ty + k * 8][tx] = W[(size_t)(by * 32 + ty + k * 8) * N + bx * 32 + tx];
  __syncthreads();
#pragma unroll
  for (int k = 0; k < 4; k++)
    WT[(size_t)(bx * 32 + ty + k * 8) * K + by * 32 + tx] = f2b(tile[tx][ty + k * 8]);
}

// --------------------------- bf16 MFMA GEMM --------------------------------

template <int BF16_OUT>
__global__ __launch_bounds__(256) void gemm_bias(
    const unsigned short* __restrict__ A, const unsigned short* __restrict__ Bt,
    const float* __restrict__ bias, void* __restrict__ Cout,
    int M, int N, int K) {
  __shared__ unsigned short As[128 * 32];
  __shared__ unsigned short Bs[128 * 32];
  const int t = threadIdx.x;
  const int lane = t & 63;
  const int wave = t >> 6;
  const int wr = wave >> 1, wc = wave & 1;
  const int rl = lane & 15, rg = lane >> 4;

  const int nbn = N >> 7;
  const int nwg = gridDim.x;                  // launched as multiple of 8
  const int bid = blockIdx.x;
  const int cpx = nwg >> 3;
  const int swz = (bid & 7) * cpx + (bid >> 3);
  const int bm = swz / nbn, bn = swz % nbn;

  const unsigned short* Ab = A + (size_t)bm * 128 * K;
  const unsigned short* Bb = Bt + (size_t)bn * 128 * K;

  f32x4 acc[4][4];
#pragma unroll
  for (int m = 0; m < 4; m++)
#pragma unroll
    for (int n = 0; n < 4; n++) acc[m][n] = (f32x4){0.f, 0.f, 0.f, 0.f};

  for (int kt = 0; kt < K; kt += 32) {
    if (kt) __syncthreads();
#pragma unroll
    for (int it = 0; it < 2; ++it) {
      int idx = it * 256 + t;
      int row = idx >> 2;
      int slot = idx & 3;
      int sl2 = slot ^ ((row >> 1) & 3);      // pre-swizzled global source
      unsigned short* ldsA = As + (size_t)(it * 256 + wave * 64) * 8; // wave-uniform
      unsigned short* ldsB = Bs + (size_t)(it * 256 + wave * 64) * 8;
      glds16(Ab + (size_t)row * K + kt + sl2 * 8, ldsA);
      glds16(Bb + (size_t)row * K + kt + sl2 * 8, ldsB);
    }
    __syncthreads();                          // drains vmcnt for gload_lds

    bf16x8 a[4], b[4];
#pragma unroll
    for (int m = 0; m < 4; m++) {
      int row = wr * 64 + m * 16 + rl;
      int sl2 = rg ^ ((row >> 1) & 3);        // swizzled read
      a[m] = *(const bf16x8*)&As[row * 32 + sl2 * 8];
    }
#pragma unroll
    for (int n = 0; n < 4; n++) {
      int row = wc * 64 + n * 16 + rl;
      int sl2 = rg ^ ((row >> 1) & 3);
      b[n] = *(const bf16x8*)&Bs[row * 32 + sl2 * 8];
    }
#pragma unroll
    for (int m = 0; m < 4; m++)
#pragma unroll
      for (int n = 0; n < 4; n++)
        acc[m][n] = mfma16(a[m], b[n], acc[m][n]);
  }

#pragma unroll
  for (int n = 0; n < 4; n++) {
    int col = bn * 128 + wc * 64 + n * 16 + rl;
    float bv = bias[col];
#pragma unroll
    for (int m = 0; m < 4; m++) {
      int row0 = bm * 128 + wr * 64 + m * 16 + rg * 4;
#pragma unroll
      for (int i = 0; i < 4; i++) {
        float v = acc[m][n][i] + bv;
        if (BF16_OUT)
          ((unsigned short*)Cout)[(size_t)(row0 + i) * N + col] = f2b(v);
        else
          ((float*)Cout)[(size_t)(row0 + i) * N + col] = v;
      }
    }
  }
}

// --------------------------- flash attention (split-K) ---------------------
// Block = (head, 64-row q-strip, key chunk of <=16 KV tiles of 64).
// 4 waves x 16 q-rows.  Swapped QK^T, double-buffered K/V LDS (XOR swizzle),
// reg-staged prefetch (T14), defer-max (T13), setprio (T5).
// Split units (qb>=16): write normalized partial O (bf16) + (m,l) f32;
// chunk 0 partial lives in ao, chunks 1..3 in pscr.  Combine kernel merges.

__global__ __launch_bounds__(256) void attn_fwd(
    const unsigned short* __restrict__ qkv, unsigned short* __restrict__ aout,
    unsigned short* __restrict__ pscr, float* __restrict__ ml) {
  __shared__ unsigned short Kb[2][64 * 64];   // K rows   [key][hd]   (swz)
  __shared__ unsigned short Vb[2][64 * 64];   // V^T rows [hd][key]   (swz)
  __shared__ unsigned short Ps[4][16 * 64];   // per-wave P / V-row scratch (swz)

  const int tid = threadIdx.x;
  const int lane = tid & 63;
  const int w = tid >> 6;
  const int rl = lane & 15, rg = lane >> 4;

  const int bid = blockIdx.x;
  const int h = bid % ATT_H;
  const int u = 159 - (bid / ATT_H);          // long chunks dispatched first
  int qb, ck;
  if (u < 16)      { qb = u;                 ck = 0; }
  else if (u < 48) { qb = 16 + ((u - 16) >> 1); ck = (u - 16) & 1; }
  else if (u < 96) { qb = 32 + (u - 48) / 3;    ck = (u - 48) % 3; }
  else             { qb = 48 + ((u - 96) >> 2); ck = (u - 96) & 3; }

  const int nt = qb + 1;                      // total KV tiles for this strip
  const int t0 = ck * 16;
  const int t1 = min(nt, t0 + 16);
  const int qbase = qb * 64 + w * 16;

  unsigned short* Pw = Ps[w];
  const int skey = lane >> 3;                 // staging: key within group of 8
  const int slot = lane & 7;                  // staging: 8-elem hd slot

  // Q fragments, in registers for the whole kernel
  bf16x8 qf[2];
#pragma unroll
  for (int ks = 0; ks < 2; ks++)
    qf[ks] = *(const bf16x8*)&qkv[(size_t)(qbase + rl) * ATT_3D + h * 64 + ks * 32 + rg * 8];

  float mS = -3.0e38f, lS = 0.f;
  f32x4 oacc[4];
#pragma unroll
  for (int hf = 0; hf < 4; hf++) oacc[hf] = (f32x4){0.f, 0.f, 0.f, 0.f};

  u16x8_t kr[2], vr[2];
  const size_t gstep = (size_t)64 * ATT_3D;
  size_t gbase = (size_t)(w * 8 + skey) * ATT_3D + 768 + h * 64 + slot * 8;

  // prologue: stage tile t0
#pragma unroll
  for (int it = 0; it < 2; ++it) {
    kr[it] = *(const u16x8_t*)&qkv[gbase + (size_t)t0 * gstep + it * 32 * ATT_3D];
    vr[it] = *(const u16x8_t*)&qkv[gbase + (size_t)t0 * gstep + it * 32 * ATT_3D + 768];
  }
  {
#pragma unroll
    for (int it = 0; it < 2; ++it) {
      int key = it * 32 + w * 8 + skey;
      *(u16x8_t*)&Kb[0][swz8(key, slot)] = kr[it];
      *(u16x8_t*)&Pw[swz8(it * 8 + skey, slot)] = vr[it];
    }
#pragma unroll
    for (int kk = 0; kk < 2; ++kk) {
      u16x8_t g;
#pragma unroll
      for (int j = 0; j < 8; j++)
        g[j] = Pw[swz8(kk * 8 + j, lane >> 3) + (lane & 7)];
      *(u16x8_t*)&Vb[0][swz8(lane, kk * 4 + w)] = g;
    }
  }
  __syncthreads();

  for (int t = t0; t < t1; ++t) {
    const int cur = t & 1;
    const bool pref = (t + 1 < t1);
    if (pref) {                               // issue next-tile loads early
      size_t gb = gbase + (size_t)(t + 1) * gstep;
#pragma unroll
      for (int it = 0; it < 2; ++it) {
        kr[it] = *(const u16x8_t*)&qkv[gb + it * 32 * ATT_3D];
        vr[it] = *(const u16x8_t*)&qkv[gb + it * 32 * ATT_3D + 768];
      }
    }

    // ---- S^T = K @ Q^T ----
    f32x4 st[4];
#pragma unroll
    for (int kf = 0; kf < 4; kf++) st[kf] = (f32x4){0.f, 0.f, 0.f, 0.f};
    __builtin_amdgcn_s_setprio(1);
#pragma unroll
    for (int ks = 0; ks < 2; ks++) {
#pragma unroll
      for (int kf = 0; kf < 4; kf++) {
        bf16x8 kfr = *(const bf16x8*)&Kb[cur][swz8(kf * 16 + rl, ks * 4 + rg)];
        st[kf] = mfma16(kfr, qf[ks], st[kf]);
      }
    }
    __builtin_amdgcn_s_setprio(0);

    if (t == nt - 1) {                        // causal mask (only last tile)
#pragma unroll
      for (int kf = 0; kf < 4; kf++)
#pragma unroll
        for (int i = 0; i < 4; i++) {
          int key = t * 64 + kf * 16 + rg * 4 + i;
          if (key > qbase + rl) st[kf][i] = -3.0e38f;
        }
    }

    // ---- online softmax (key axis lane-local + 2 shuffles) ----
    float pm = st[0][0];
#pragma unroll
    for (int kf = 0; kf < 4; kf++)
#pragma unroll
      for (int i = 0; i < 4; i++) pm = fmaxf(pm, st[kf][i]);
    pm = fmaxf(pm, __shfl_xor(pm, 16, 64));
    pm = fmaxf(pm, __shfl_xor(pm, 32, 64));
    if (!__all(pm - mS <= 8.f)) {             // defer-max: rescale rarely
      float mn = fmaxf(mS, pm);
      float fac = __expf(mS - mn);
      mS = mn;
      lS *= fac;
#pragma unroll
      for (int i = 0; i < 4; i++) {
        float fi = __shfl(fac, rg * 4 + i, 64);
#pragma unroll
        for (int hf = 0; hf < 4; hf++) oacc[hf][i] *= fi;
      }
    }
    const float mC = mS * LOG2E;              // exp(s-m) = exp2(s*log2e - mC)
    float psum = 0.f;
#pragma unroll
    for (int kf = 0; kf < 4; kf++) {
      u16x4_t pw4;
#pragma unroll
      for (int i = 0; i < 4; i++) {
        float p = __builtin_amdgcn_exp2f(fmaf(st[kf][i], LOG2E, -mC));
        psum += p;
        pw4[i] = f2b(p);
      }
      *(u16x4_t*)&Pw[swz8(rl, kf * 2 + (rg >> 1)) + (rg & 1) * 4] = pw4;
    }
    psum += __shfl_xor(psum, 16, 64);
    psum += __shfl_xor(psum, 32, 64);
    lS += psum;

    // ---- PV : O += P @ V ----
    __builtin_amdgcn_s_setprio(1);
#pragma unroll
    for (int ks2 = 0; ks2 < 2; ks2++) {
      bf16x8 pa = *(const bf16x8*)&Pw[swz8(rl, ks2 * 4 + rg)];
#pragma unroll
      for (int hf = 0; hf < 4; hf++) {
        bf16x8 vbf = *(const bf16x8*)&Vb[cur][swz8(hf * 16 + rl, ks2 * 4 + rg)];
        oacc[hf] = mfma16(pa, vbf, oacc[hf]);
      }
    }
    __builtin_amdgcn_s_setprio(0);

    if (pref) {                               // write-late: LDS for t+1
      const int nxt = cur ^ 1;
#pragma unroll
      for (int it = 0; it < 2; ++it) {
        int key = it * 32 + w * 8 + skey;
        *(u16x8_t*)&Kb[nxt][swz8(key, slot)] = kr[it];
        *(u16x8_t*)&Pw[swz8(it * 8 + skey, slot)] = vr[it];
      }
#pragma unroll
      for (int kk = 0; kk < 2; ++kk) {        // within-wave V transpose
        u16x8_t g;
#pragma unroll
        for (int j = 0; j < 8; j++)
          g[j] = Pw[swz8(kk * 8 + j, lane >> 3) + (lane & 7)];
        *(u16x8_t*)&Vb[nxt][swz8(lane, kk * 4 + w)] = g;
      }
    }
    __syncthreads();                          // one barrier per tile
  }

  // ---- epilogue: write normalized O (final or partial) ----
  const bool split = (qb >= 16);
  unsigned short* dst;
  int pitch;
  if (!split || ck == 0) {
    dst = aout + (size_t)(qb * 64) * ATT_D + h * 64;
    pitch = ATT_D;
  } else {
    int s;
    if (qb < 32)      s = h * 96 + (qb - 16);
    else if (qb < 48) s = h * 96 + 16 + (qb - 32) * 2 + (ck - 1);
    else              s = h * 96 + 48 + (qb - 48) * 3 + (ck - 1);
    dst = pscr + (size_t)s * 4096;
    pitch = 64;
  }
  if (split && rg == 0) {                     // (m,l) per q-row, once
    int unit = h * 48 + (qb - 16);
    float2* mlp = (float2*)ml;
    mlp[(unit * 4 + ck) * 64 + w * 16 + rl] = make_float2(mS, lS);
  }
#pragma unroll
  for (int i = 0; i < 4; i++) {
    float li = __shfl(lS, rg * 4 + i, 64);
    float inv = 1.f / li;
    int qrow = w * 16 + rg * 4 + i;
#pragma unroll
    for (int hf = 0; hf < 4; hf++)
      dst[(size_t)qrow * pitch + hf * 16 + rl] = f2b(oacc[hf][i] * inv);
  }
}

// --------------------------- split-K combine -------------------------------
// One block per split unit (h, qb>=16).  256 thr: thread = (q, 16-col part).

__global__ __launch_bounds__(256) void attn_combine(
    const unsigned short* __restrict__ pscr, const float* __restrict__ ml,
    unsigned short* __restrict__ ao) {
  const int unit = blockIdx.x;                // 576 = 12 * 48
  const int h = unit / 48, uqb = unit % 48, qb = uqb + 16;
  const int nch = (qb + 16) >> 4;             // ceil((qb+1)/16), 2..4
  const int tid = threadIdx.x;
  const int q = tid >> 2, part = tid & 3;

  const float2* mlp = (const float2*)ml;
  float m[4], l[4];
  float M = -3.0e38f;
  for (int c = 0; c < nch; ++c) {
    float2 p = mlp[(unit * 4 + c) * 64 + q];
    m[c] = p.x; l[c] = p.y;
    M = fmaxf(M, m[c]);
  }
  float wgt[4], den = 0.f;
  for (int c = 0; c < nch; ++c) {
    wgt[c] = l[c] * __expf(m[c] - M);
    den += wgt[c];
  }

  float acc[16];
#pragma unroll
  for (int j = 0; j < 16; j++) acc[j] = 0.f;

  unsigned short* aorow = ao + (size_t)(qb * 64 + q) * ATT_D + h * 64 + part * 16;
  for (int c = 0; c < nch; ++c) {
    const unsigned short* src;
    if (c == 0) {
      src = aorow;
    } else {
      int s;
      if (qb < 32)      s = h * 96 + (qb - 16);
      else if (qb < 48) s = h * 96 + 16 + (qb - 32) * 2 + (c - 1);
      else              s = h * 96 + 48 + (qb - 48) * 3 + (c - 1);
      src = pscr + (size_t)s * 4096 + q * 64 + part * 16;
    }
    u16x8_t v0 = *(const u16x8_t*)src;
    u16x8_t v1 = *(const u16x8_t*)(src + 8);
#pragma unroll
    for (int j = 0; j < 8; j++) acc[j] += wgt[c] * b2f(v0[j]);
#pragma unroll
    for (int j = 0; j < 8; j++) acc[8 + j] += wgt[c] * b2f(v1[j]);
  }
  float inv = 1.f / den;
  u16x8_t o0, o1;
#pragma unroll
  for (int j = 0; j < 8; j++) { o0[j] = f2b(acc[j] * inv); o1[j] = f2b(acc[8 + j] * inv); }
  *(u16x8_t*)aorow = o0;
  *(u16x8_t*)(aorow + 8) = o1;
}

// ------------------------------- launcher ----------------------------------

extern "C" void kernel_launch(void* const* d_in, const int* in_sizes, int n_in,
                              void* d_out, int out_size, void* d_ws, size_t ws_size,
                              hipStream_t stream) {
  const float* x      = (const float*)d_in[0];
  const float* W_attn = (const float*)d_in[1];
  const float* b_attn = (const float*)d_in[2];
  const float* W_proj = (const float*)d_in[3];
  const float* b_proj = (const float*)d_in[4];
  float* out = (float*)d_out;

  char* ws = (char*)d_ws;
  unsigned short* xb  = (unsigned short*)(ws);              //  6,291,456 B
  unsigned short* WaT = (unsigned short*)(ws + 6291456);    //  3,538,944 B
  unsigned short* WpT = (unsigned short*)(ws + 9830400);    //  1,179,648 B
  unsigned short* qkv = (unsigned short*)(ws + 11010048);   // 18,874,368 B
  unsigned short* ao  = (unsigned short*)(ws + 29884416);   //  6,291,456 B
  // split-K scratch (aliases regions that are dead during attention):
  unsigned short* pscr = (unsigned short*)(ws);             // 9,437,184 B (xb+WaT)
  float*          ml   = (float*)(ws + 9830400);            // 1,179,648 B (WpT)

  convert_f32_bf16<<<3072, 256, 0, stream>>>(x, xb, 786432);           // 4096*768/4
  transpose_conv<<<dim3(72, 24), 256, 0, stream>>>(W_attn, WaT, 768, 2304);

  gemm_bias<1><<<576, 256, 0, stream>>>(xb, WaT, b_attn, qkv, 4096, 2304, 768);
  attn_fwd<<<1920, 256, 0, stream>>>(qkv, ao, pscr, ml);
  attn_combine<<<576, 256, 0, stream>>>(pscr, ml, ao);

  // WpT region doubled as ml during attention; transpose W_proj only now.
  transpose_conv<<<dim3(24, 24), 256, 0, stream>>>(W_proj, WpT, 768, 768);
  gemm_bias<0><<<192, 256, 0, stream>>>(ao, WpT, b_proj, out, 4096, 768, 768);
}